// Round 1
// baseline (482.974 us; speedup 1.0000x reference)
//
#include <hip/hip_runtime.h>
#include <hip/hip_bf16.h>
#include <stdint.h>

#define B_ 8
#define L_ 2048
#define D_ 256

typedef unsigned short u16;
typedef __attribute__((ext_vector_type(4))) float f32x4;
typedef __attribute__((ext_vector_type(8))) short bf16x8;

__device__ __forceinline__ u16 f2b(float f) {
  union { float f; unsigned u; } v; v.f = f;
  unsigned r = v.u + 0x7FFFu + ((v.u >> 16) & 1u);
  return (u16)(r >> 16);
}

__device__ __forceinline__ void async_copy16(const void* g, u16* l) {
  __builtin_amdgcn_global_load_lds(
      (const __attribute__((address_space(1))) unsigned*)g,
      (__attribute__((address_space(3))) unsigned*)l,
      16, 0, 0);
}

// ---- shared GEMM core: C[128x128] tile, A[M,K]·B[N,K]^T, K contiguous ----
template<int KD>
__device__ __forceinline__ void gemm_core(const u16* __restrict__ Ag,
                                          const u16* __restrict__ Bg,
                                          int tile_m, int tile_n,
                                          u16* lds_a, u16* lds_b,
                                          f32x4 acc[4][4]) {
  const int tid  = threadIdx.x;
  const int wave = tid >> 6, lane = tid & 63;
  const int qd = lane >> 4, ln = lane & 15;
  const int wm = wave >> 1, wn = wave & 1;
  const int lrow = lane >> 2;         // 0..15
  const int lcol = (lane & 3) * 8;    // element offset (16B chunks)
  const u16* Abase = Ag + (size_t)tile_m * KD + lcol;
  const u16* Bbase = Bg + (size_t)tile_n * KD + lcol;

  for (int k0 = 0; k0 < KD; k0 += 32) {
#pragma unroll
    for (int j = 0; j < 2; ++j) {
      const int r0 = j * 64 + wave * 16;   // wave-uniform
      async_copy16(Abase + (size_t)(r0 + lrow) * KD + k0, lds_a + r0 * 32);
      async_copy16(Bbase + (size_t)(r0 + lrow) * KD + k0, lds_b + r0 * 32);
    }
    __syncthreads();
    bf16x8 af[4], bg[4];
#pragma unroll
    for (int i = 0; i < 4; ++i) {
      af[i] = *(const bf16x8*)(lds_a + (wm * 64 + i * 16 + ln) * 32 + qd * 8);
      bg[i] = *(const bf16x8*)(lds_b + (wn * 64 + i * 16 + ln) * 32 + qd * 8);
    }
#pragma unroll
    for (int i = 0; i < 4; ++i)
#pragma unroll
      for (int j = 0; j < 4; ++j)
        acc[i][j] = __builtin_amdgcn_mfma_f32_16x16x32_bf16(af[i], bg[j], acc[i][j], 0, 0, 0);
    __syncthreads();
  }
}

// ---- 1. convert x and W to bf16 ----
__global__ __launch_bounds__(256) void cvt_kernel(const float* __restrict__ x,
    const float* __restrict__ Wq, const float* __restrict__ Wk, const float* __restrict__ Wv,
    u16* __restrict__ xb, u16* __restrict__ Wb) {
  const int i = blockIdx.x * 256 + threadIdx.x;  // float4 index
  const int NX4 = (B_ * L_ * D_) / 4;            // 1,048,576
  f32x4 v;
  u16* dst;
  if (i < NX4) {
    v = ((const f32x4*)x)[i];
    dst = xb + (size_t)i * 4;
  } else {
    int wi = i - NX4;                 // 0..49151
    int z = wi >> 14;                 // which W (16384 f4 each)
    int off = wi & 16383;
    const float* W = (z == 0) ? Wq : (z == 1 ? Wk : Wv);
    v = ((const f32x4*)W)[off];
    dst = Wb + (size_t)z * 65536 + (size_t)off * 4;
  }
  unsigned p0 = (unsigned)f2b(v.x) | ((unsigned)f2b(v.y) << 16);
  unsigned p1 = (unsigned)f2b(v.z) | ((unsigned)f2b(v.w) << 16);
  *(uint2*)dst = make_uint2(p0, p1);
}

// ---- 2. QKV projection: y = x @ W^T + b ----
__global__ __launch_bounds__(256) void qkv_gemm(const u16* __restrict__ xb, const u16* __restrict__ Wb,
    const float* __restrict__ bq, const float* __restrict__ bk, const float* __restrict__ bv,
    u16* __restrict__ Qb, u16* __restrict__ Kb, u16* __restrict__ Vb,
    float* __restrict__ out_sp) {
  __shared__ u16 lds_a[128 * 32], lds_b[128 * 32];
  const int z = blockIdx.z;
  const float* bias = (z == 0) ? bq : (z == 1 ? bk : bv);
  u16* dst = (z == 0) ? Qb : (z == 1 ? Kb : Vb);
  const int tile_m = blockIdx.x * 128, tile_n = blockIdx.y * 128;
  f32x4 acc[4][4];
#pragma unroll
  for (int i = 0; i < 4; ++i)
#pragma unroll
    for (int j = 0; j < 4; ++j) acc[i][j] = (f32x4){0.f, 0.f, 0.f, 0.f};
  gemm_core<256>(xb, Wb + (size_t)z * 256 * 256, tile_m, tile_n, lds_a, lds_b, acc);

  const int lane = threadIdx.x & 63, wave = threadIdx.x >> 6;
  const int qd = lane >> 4, ln = lane & 15, wm = wave >> 1, wn = wave & 1;
#pragma unroll
  for (int i = 0; i < 4; ++i)
#pragma unroll
    for (int j = 0; j < 4; ++j) {
      const int col = tile_n + wn * 64 + j * 16 + ln;
      const float bvv = bias[col];
      const int row0 = tile_m + wm * 64 + i * 16 + qd * 4;
#pragma unroll
      for (int r = 0; r < 4; ++r) {
        const int row = row0 + r;
        const float val = acc[i][j][r] + bvv;
        dst[(size_t)row * D_ + col] = f2b(val);
        if (z == 0) {
          const int bb = row >> 11, l = row & 2047;
          out_sp[((size_t)bb * (2 * L_) + l) * D_ + col] = val;
        }
      }
    }
}

// ---- 3. transpose V (per batch [L,D] -> [D,L]) ----
__global__ __launch_bounds__(256) void transpose_v(const u16* __restrict__ Vb, u16* __restrict__ Vbt) {
  const int b = blockIdx.z;
  const int l0 = blockIdx.x * 64;
  const int d0 = blockIdx.y * 64;
  __shared__ u16 t[64][65];
  const int tx = threadIdx.x & 63;
  const int ty = threadIdx.x >> 6;
  const u16* src = Vb + (size_t)b * L_ * D_;
  for (int j = ty; j < 64; j += 4)
    t[j][tx] = src[(size_t)(l0 + j) * D_ + d0 + tx];
  __syncthreads();
  u16* dst = Vbt + (size_t)b * D_ * L_;
  for (int j = ty; j < 64; j += 4)
    dst[(size_t)(d0 + j) * L_ + l0 + tx] = t[tx][j];
}

// ---- 4. E = Q K^T / 16 ----
__global__ __launch_bounds__(256) void e_gemm(const u16* __restrict__ Qb, const u16* __restrict__ Kb,
                                              float* __restrict__ Ebuf) {
  __shared__ u16 lds_a[128 * 32], lds_b[128 * 32];
  const int b = blockIdx.z;
  const int tile_m = blockIdx.x * 128, tile_n = blockIdx.y * 128;
  f32x4 acc[4][4];
#pragma unroll
  for (int i = 0; i < 4; ++i)
#pragma unroll
    for (int j = 0; j < 4; ++j) acc[i][j] = (f32x4){0.f, 0.f, 0.f, 0.f};
  gemm_core<256>(Qb + (size_t)b * L_ * D_, Kb + (size_t)b * L_ * D_, tile_m, tile_n, lds_a, lds_b, acc);

  float* Eb = Ebuf + (size_t)b * L_ * L_;
  const int lane = threadIdx.x & 63, wave = threadIdx.x >> 6;
  const int qd = lane >> 4, ln = lane & 15, wm = wave >> 1, wn = wave & 1;
#pragma unroll
  for (int i = 0; i < 4; ++i)
#pragma unroll
    for (int j = 0; j < 4; ++j) {
      const int col = tile_n + wn * 64 + j * 16 + ln;
      const int row0 = tile_m + wm * 64 + i * 16 + qd * 4;
#pragma unroll
      for (int r = 0; r < 4; ++r)
        Eb[(size_t)(row0 + r) * L_ + col] = acc[i][j][r] * 0.0625f;
    }
}

// ---- 5. column softmax stats: softmax over q (rows) per (b,k) ----
__global__ __launch_bounds__(256) void stats_kernel(const float* __restrict__ E,
                                                    float* __restrict__ mOut, float* __restrict__ rOut) {
  const int b = blockIdx.y;
  const int col = blockIdx.x * 64 + (threadIdx.x & 63);
  const int part = threadIdx.x >> 6;
  const float* Eb = E + (size_t)b * L_ * L_;
  float m = -1e30f, s = 0.f;
  for (int q = part; q < L_; q += 4) {
    float e = Eb[(size_t)q * L_ + col];
    float mn = fmaxf(m, e);
    s = s * __expf(m - mn) + __expf(e - mn);
    m = mn;
  }
  __shared__ float lm[256], ls[256];
  lm[threadIdx.x] = m;
  ls[threadIdx.x] = s;
  __syncthreads();
  if (part == 0) {
    float M = m, S = s;
#pragma unroll
    for (int p = 1; p < 4; ++p) {
      float m2 = lm[p * 64 + (threadIdx.x & 63)], s2 = ls[p * 64 + (threadIdx.x & 63)];
      float mn = fmaxf(M, m2);
      S = S * __expf(M - mn) + s2 * __expf(m2 - mn);
      M = mn;
    }
    mOut[(size_t)b * L_ + col] = M;
    rOut[(size_t)b * L_ + col] = 1.0f / S;
  }
}

// ---- 6. apply softmax: A = exp(E-m)*r in place, plus bf16 copy ----
__global__ __launch_bounds__(256) void apply_kernel(float* __restrict__ EA, u16* __restrict__ Ab,
                                                    const float* __restrict__ mArr,
                                                    const float* __restrict__ rArr) {
  const size_t i4 = (size_t)blockIdx.x * 256 + threadIdx.x;  // float4 index
  const int k4 = (int)(i4 & 511);
  const size_t row = i4 >> 9;       // b*2048 + q
  const int b = (int)(row >> 11);
  f32x4 e = ((const f32x4*)EA)[i4];
  const f32x4 mv = *(const f32x4*)(mArr + (size_t)b * L_ + k4 * 4);
  const f32x4 rv = *(const f32x4*)(rArr + (size_t)b * L_ + k4 * 4);
  f32x4 a;
  a.x = __expf(e.x - mv.x) * rv.x;
  a.y = __expf(e.y - mv.y) * rv.y;
  a.z = __expf(e.z - mv.z) * rv.z;
  a.w = __expf(e.w - mv.w) * rv.w;
  ((f32x4*)EA)[i4] = a;
  unsigned p0 = (unsigned)f2b(a.x) | ((unsigned)f2b(a.y) << 16);
  unsigned p1 = (unsigned)f2b(a.z) | ((unsigned)f2b(a.w) << 16);
  *(uint2*)(Ab + i4 * 4) = make_uint2(p0, p1);
}

// ---- 7. C = A V  (B-operand = V^T, rows d, k contiguous) ----
__global__ __launch_bounds__(256) void av_gemm(const u16* __restrict__ Ab, const u16* __restrict__ Vbt,
                                               float* __restrict__ out_sp) {
  __shared__ u16 lds_a[128 * 32], lds_b[128 * 32];
  const int b = blockIdx.z;
  const int tile_m = blockIdx.x * 128, tile_n = blockIdx.y * 128;
  f32x4 acc[4][4];
#pragma unroll
  for (int i = 0; i < 4; ++i)
#pragma unroll
    for (int j = 0; j < 4; ++j) acc[i][j] = (f32x4){0.f, 0.f, 0.f, 0.f};
  gemm_core<2048>(Ab + (size_t)b * L_ * L_, Vbt + (size_t)b * D_ * L_, tile_m, tile_n, lds_a, lds_b, acc);

  const int lane = threadIdx.x & 63, wave = threadIdx.x >> 6;
  const int qd = lane >> 4, ln = lane & 15, wm = wave >> 1, wn = wave & 1;
#pragma unroll
  for (int i = 0; i < 4; ++i)
#pragma unroll
    for (int j = 0; j < 4; ++j) {
      const int col = tile_n + wn * 64 + j * 16 + ln;
      const int row0 = tile_m + wm * 64 + i * 16 + qd * 4;
#pragma unroll
      for (int r = 0; r < 4; ++r)
        out_sp[((size_t)b * (2 * L_) + L_ + row0 + r) * D_ + col] = acc[i][j][r];
    }
}

extern "C" void kernel_launch(void* const* d_in, const int* in_sizes, int n_in,
                              void* d_out, int out_size, void* d_ws, size_t ws_size,
                              hipStream_t stream) {
  const float* x  = (const float*)d_in[0];
  const float* Wq = (const float*)d_in[1];
  const float* bq = (const float*)d_in[2];
  const float* Wk = (const float*)d_in[3];
  const float* bk = (const float*)d_in[4];
  const float* Wv = (const float*)d_in[5];
  const float* bv = (const float*)d_in[6];

  float* out    = (float*)d_out;                      // S_p: 8*4096*256 floats
  float* outA   = out + (size_t)B_ * (2 * L_) * D_;   // A region: 8*2048*2048 (holds E then A)

  // workspace layout (u16 elements)
  u16* w   = (u16*)d_ws;
  u16* xb  = w;                    // 4,194,304
  u16* Wb  = xb + 4194304;         //   196,608
  u16* Qb  = Wb + 196608;          // 4,194,304
  u16* Kb  = Qb + 4194304;         // 4,194,304
  u16* Vb  = Kb + 4194304;         // 4,194,304
  u16* Vbt = Vb + 4194304;         // 4,194,304
  u16* Ab  = Vbt + 4194304;        // 33,554,432
  float* mArr = (float*)(Ab + 33554432);
  float* rArr = mArr + B_ * L_;

  cvt_kernel<<<4288, 256, 0, stream>>>(x, Wq, Wk, Wv, xb, Wb);
  qkv_gemm<<<dim3(128, 2, 3), 256, 0, stream>>>(xb, Wb, bq, bk, bv, Qb, Kb, Vb, out);
  transpose_v<<<dim3(32, 4, 8), 256, 0, stream>>>(Vb, Vbt);
  e_gemm<<<dim3(16, 16, 8), 256, 0, stream>>>(Qb, Kb, outA);
  stats_kernel<<<dim3(32, 8), 256, 0, stream>>>(outA, mArr, rArr);
  apply_kernel<<<32768, 256, 0, stream>>>(outA, Ab, mArr, rArr);
  av_gemm<<<dim3(16, 2, 8), 256, 0, stream>>>(Ab, Vbt, out);
}

// Round 2
// 337.258 us; speedup vs baseline: 1.4321x; 1.4321x over previous
//
#include <hip/hip_runtime.h>
#include <hip/hip_bf16.h>
#include <stdint.h>

#define B_ 8
#define L_ 2048
#define D_ 256

typedef unsigned short u16;
typedef __attribute__((ext_vector_type(4))) float f32x4;
typedef __attribute__((ext_vector_type(8))) short bf16x8;

__device__ __forceinline__ u16 f2b(float f) {
  union { float f; unsigned u; } v; v.f = f;
  unsigned r = v.u + 0x7FFFu + ((v.u >> 16) & 1u);
  return (u16)(r >> 16);
}

__device__ __forceinline__ void comb(float& m, float& s, float m2, float s2) {
  float mn = fmaxf(m, m2);
  s = s * __expf(m - mn) + s2 * __expf(m2 - mn);
  m = mn;
}

__device__ __forceinline__ void async_copy16(const void* g, u16* l) {
  __builtin_amdgcn_global_load_lds(
      (const __attribute__((address_space(1))) unsigned*)g,
      (__attribute__((address_space(3))) unsigned*)l,
      16, 0, 0);
}

// ---- shared GEMM core: C[128x128] tile, A[M,K]·B[N,K]^T, K contiguous ----
template<int KD>
__device__ __forceinline__ void gemm_core(const u16* __restrict__ Ag,
                                          const u16* __restrict__ Bg,
                                          int tile_m, int tile_n,
                                          u16* lds_a, u16* lds_b,
                                          f32x4 acc[4][4]) {
  const int tid  = threadIdx.x;
  const int wave = tid >> 6, lane = tid & 63;
  const int qd = lane >> 4, ln = lane & 15;
  const int wm = wave >> 1, wn = wave & 1;
  const int lrow = lane >> 2;         // 0..15
  const int lcol = (lane & 3) * 8;    // element offset (16B chunks)
  const u16* Abase = Ag + (size_t)tile_m * KD + lcol;
  const u16* Bbase = Bg + (size_t)tile_n * KD + lcol;

  for (int k0 = 0; k0 < KD; k0 += 32) {
#pragma unroll
    for (int j = 0; j < 2; ++j) {
      const int r0 = j * 64 + wave * 16;   // wave-uniform
      async_copy16(Abase + (size_t)(r0 + lrow) * KD + k0, lds_a + r0 * 32);
      async_copy16(Bbase + (size_t)(r0 + lrow) * KD + k0, lds_b + r0 * 32);
    }
    __syncthreads();
    bf16x8 af[4], bg[4];
#pragma unroll
    for (int i = 0; i < 4; ++i) {
      af[i] = *(const bf16x8*)(lds_a + (wm * 64 + i * 16 + ln) * 32 + qd * 8);
      bg[i] = *(const bf16x8*)(lds_b + (wn * 64 + i * 16 + ln) * 32 + qd * 8);
    }
#pragma unroll
    for (int i = 0; i < 4; ++i)
#pragma unroll
      for (int j = 0; j < 4; ++j)
        acc[i][j] = __builtin_amdgcn_mfma_f32_16x16x32_bf16(af[i], bg[j], acc[i][j], 0, 0, 0);
    __syncthreads();
  }
}

// ---- 1. convert x and W to bf16 ----
__global__ __launch_bounds__(256) void cvt_kernel(const float* __restrict__ x,
    const float* __restrict__ Wq, const float* __restrict__ Wk, const float* __restrict__ Wv,
    u16* __restrict__ xb, u16* __restrict__ Wb) {
  const int i = blockIdx.x * 256 + threadIdx.x;  // float4 index
  const int NX4 = (B_ * L_ * D_) / 4;            // 1,048,576
  f32x4 v;
  u16* dst;
  if (i < NX4) {
    v = ((const f32x4*)x)[i];
    dst = xb + (size_t)i * 4;
  } else {
    int wi = i - NX4;                 // 0..49151
    int z = wi >> 14;                 // which W (16384 f4 each)
    int off = wi & 16383;
    const float* W = (z == 0) ? Wq : (z == 1 ? Wk : Wv);
    v = ((const f32x4*)W)[off];
    dst = Wb + (size_t)z * 65536 + (size_t)off * 4;
  }
  unsigned p0 = (unsigned)f2b(v.x) | ((unsigned)f2b(v.y) << 16);
  unsigned p1 = (unsigned)f2b(v.z) | ((unsigned)f2b(v.w) << 16);
  *(uint2*)dst = make_uint2(p0, p1);
}

// ---- 2. QKV projection: y = x @ W^T + b ----
__global__ __launch_bounds__(256) void qkv_gemm(const u16* __restrict__ xb, const u16* __restrict__ Wb,
    const float* __restrict__ bq, const float* __restrict__ bk, const float* __restrict__ bv,
    u16* __restrict__ Qb, u16* __restrict__ Kb, u16* __restrict__ Vb,
    float* __restrict__ out_sp) {
  __shared__ u16 lds_a[128 * 32], lds_b[128 * 32];
  const int z = blockIdx.z;
  const float* bias = (z == 0) ? bq : (z == 1 ? bk : bv);
  u16* dst = (z == 0) ? Qb : (z == 1 ? Kb : Vb);
  const int tile_m = blockIdx.x * 128, tile_n = blockIdx.y * 128;
  f32x4 acc[4][4];
#pragma unroll
  for (int i = 0; i < 4; ++i)
#pragma unroll
    for (int j = 0; j < 4; ++j) acc[i][j] = (f32x4){0.f, 0.f, 0.f, 0.f};
  gemm_core<256>(xb, Wb + (size_t)z * 256 * 256, tile_m, tile_n, lds_a, lds_b, acc);

  const int lane = threadIdx.x & 63, wave = threadIdx.x >> 6;
  const int qd = lane >> 4, ln = lane & 15, wm = wave >> 1, wn = wave & 1;
#pragma unroll
  for (int i = 0; i < 4; ++i)
#pragma unroll
    for (int j = 0; j < 4; ++j) {
      const int col = tile_n + wn * 64 + j * 16 + ln;
      const float bvv = bias[col];
      const int row0 = tile_m + wm * 64 + i * 16 + qd * 4;
#pragma unroll
      for (int r = 0; r < 4; ++r) {
        const int row = row0 + r;
        const float val = acc[i][j][r] + bvv;
        dst[(size_t)row * D_ + col] = f2b(val);
        if (z == 0) {
          const int bb = row >> 11, l = row & 2047;
          out_sp[((size_t)bb * (2 * L_) + l) * D_ + col] = val;
        }
      }
    }
}

// ---- 3. transpose V (per batch [L,D] -> [D,L]) ----
__global__ __launch_bounds__(256) void transpose_v(const u16* __restrict__ Vb, u16* __restrict__ Vbt) {
  const int b = blockIdx.z;
  const int l0 = blockIdx.x * 64;
  const int d0 = blockIdx.y * 64;
  __shared__ u16 t[64][65];
  const int tx = threadIdx.x & 63;
  const int ty = threadIdx.x >> 6;
  const u16* src = Vb + (size_t)b * L_ * D_;
  for (int j = ty; j < 64; j += 4)
    t[j][tx] = src[(size_t)(l0 + j) * D_ + d0 + tx];
  __syncthreads();
  u16* dst = Vbt + (size_t)b * D_ * L_;
  for (int j = ty; j < 64; j += 4)
    dst[(size_t)(d0 + j) * L_ + l0 + tx] = t[tx][j];
}

// ---- 4. E = Q K^T / 16, fused per-tile column-softmax partials ----
// partial layout: pm/ps[tile_mi(16)][b(8)][col(2048)]
__global__ __launch_bounds__(256) void e_gemm(const u16* __restrict__ Qb, const u16* __restrict__ Kb,
                                              float* __restrict__ Ebuf,
                                              float* __restrict__ pm, float* __restrict__ ps) {
  __shared__ u16 lds_a[128 * 32], lds_b[128 * 32];
  __shared__ float sm_m[4][64], sm_s[4][64];
  const int b = blockIdx.z;
  const int tile_m = blockIdx.x * 128, tile_n = blockIdx.y * 128;
  f32x4 acc[4][4];
#pragma unroll
  for (int i = 0; i < 4; ++i)
#pragma unroll
    for (int j = 0; j < 4; ++j) acc[i][j] = (f32x4){0.f, 0.f, 0.f, 0.f};
  gemm_core<256>(Qb + (size_t)b * L_ * D_, Kb + (size_t)b * L_ * D_, tile_m, tile_n, lds_a, lds_b, acc);

  float* Eb = Ebuf + (size_t)b * L_ * L_;
  const int tid = threadIdx.x;
  const int lane = tid & 63, wave = tid >> 6;
  const int qd = lane >> 4, ln = lane & 15, wm = wave >> 1, wn = wave & 1;
#pragma unroll
  for (int j = 0; j < 4; ++j) {
    const int col = tile_n + wn * 64 + j * 16 + ln;
    const int row0 = tile_m + wm * 64 + qd * 4;
    float m = -1e30f;
#pragma unroll
    for (int i = 0; i < 4; ++i)
#pragma unroll
      for (int r = 0; r < 4; ++r)
        m = fmaxf(m, acc[i][j][r] * 0.0625f);
    float s = 0.f;
#pragma unroll
    for (int i = 0; i < 4; ++i)
#pragma unroll
      for (int r = 0; r < 4; ++r) {
        const float e = acc[i][j][r] * 0.0625f;
        Eb[(size_t)(row0 + i * 16 + r) * L_ + col] = e;
        s += __expf(e - m);
      }
    comb(m, s, __shfl_xor(m, 16), __shfl_xor(s, 16));
    comb(m, s, __shfl_xor(m, 32), __shfl_xor(s, 32));
    if (qd == 0) { sm_m[wave][j * 16 + ln] = m; sm_s[wave][j * 16 + ln] = s; }
  }
  __syncthreads();
  if (tid < 128) {
    const int w = tid >> 6, c = tid & 63;   // w = wn, columns wn*64 + c
    float m = sm_m[w][c], s = sm_s[w][c];
    comb(m, s, sm_m[w + 2][c], sm_s[w + 2][c]);
    const size_t idx = (size_t)blockIdx.x * (B_ * L_) + (size_t)b * L_ + tile_n + w * 64 + c;
    pm[idx] = m;
    ps[idx] = s;
  }
}

// ---- 5. reduce 16 tile partials -> m, r=1/s per (b,col) ----
__global__ __launch_bounds__(256) void stats_reduce(const float* __restrict__ pm,
                                                    const float* __restrict__ ps,
                                                    float* __restrict__ mOut, float* __restrict__ rOut) {
  const int idx = blockIdx.x * 256 + threadIdx.x;  // 0..16383 = b*2048+col
  float m = -1e30f, s = 0.f;
#pragma unroll
  for (int t = 0; t < 16; ++t)
    comb(m, s, pm[t * (B_ * L_) + idx], ps[t * (B_ * L_) + idx]);
  mOut[idx] = m;
  rOut[idx] = 1.0f / s;
}

// ---- 6. apply softmax: A = exp(E-m)*r in place, plus bf16 copy ----
__global__ __launch_bounds__(256) void apply_kernel(float* __restrict__ EA, u16* __restrict__ Ab,
                                                    const float* __restrict__ mArr,
                                                    const float* __restrict__ rArr) {
  const size_t i4 = (size_t)blockIdx.x * 256 + threadIdx.x;  // float4 index
  const int k4 = (int)(i4 & 511);
  const size_t row = i4 >> 9;       // b*2048 + q
  const int b = (int)(row >> 11);
  f32x4 e = ((const f32x4*)EA)[i4];
  const f32x4 mv = *(const f32x4*)(mArr + (size_t)b * L_ + k4 * 4);
  const f32x4 rv = *(const f32x4*)(rArr + (size_t)b * L_ + k4 * 4);
  f32x4 a;
  a.x = __expf(e.x - mv.x) * rv.x;
  a.y = __expf(e.y - mv.y) * rv.y;
  a.z = __expf(e.z - mv.z) * rv.z;
  a.w = __expf(e.w - mv.w) * rv.w;
  ((f32x4*)EA)[i4] = a;
  unsigned p0 = (unsigned)f2b(a.x) | ((unsigned)f2b(a.y) << 16);
  unsigned p1 = (unsigned)f2b(a.z) | ((unsigned)f2b(a.w) << 16);
  *(uint2*)(Ab + i4 * 4) = make_uint2(p0, p1);
}

// ---- 7. C = A V  (B-operand = V^T, rows d, k contiguous) ----
__global__ __launch_bounds__(256) void av_gemm(const u16* __restrict__ Ab, const u16* __restrict__ Vbt,
                                               float* __restrict__ out_sp) {
  __shared__ u16 lds_a[128 * 32], lds_b[128 * 32];
  const int b = blockIdx.z;
  const int tile_m = blockIdx.x * 128, tile_n = blockIdx.y * 128;
  f32x4 acc[4][4];
#pragma unroll
  for (int i = 0; i < 4; ++i)
#pragma unroll
    for (int j = 0; j < 4; ++j) acc[i][j] = (f32x4){0.f, 0.f, 0.f, 0.f};
  gemm_core<2048>(Ab + (size_t)b * L_ * L_, Vbt + (size_t)b * D_ * L_, tile_m, tile_n, lds_a, lds_b, acc);

  const int lane = threadIdx.x & 63, wave = threadIdx.x >> 6;
  const int qd = lane >> 4, ln = lane & 15, wm = wave >> 1, wn = wave & 1;
#pragma unroll
  for (int i = 0; i < 4; ++i)
#pragma unroll
    for (int j = 0; j < 4; ++j) {
      const int col = tile_n + wn * 64 + j * 16 + ln;
      const int row0 = tile_m + wm * 64 + i * 16 + qd * 4;
#pragma unroll
      for (int r = 0; r < 4; ++r)
        out_sp[((size_t)b * (2 * L_) + L_ + row0 + r) * D_ + col] = acc[i][j][r];
    }
}

extern "C" void kernel_launch(void* const* d_in, const int* in_sizes, int n_in,
                              void* d_out, int out_size, void* d_ws, size_t ws_size,
                              hipStream_t stream) {
  const float* x  = (const float*)d_in[0];
  const float* Wq = (const float*)d_in[1];
  const float* bq = (const float*)d_in[2];
  const float* Wk = (const float*)d_in[3];
  const float* bk = (const float*)d_in[4];
  const float* Wv = (const float*)d_in[5];
  const float* bv = (const float*)d_in[6];

  float* out    = (float*)d_out;                      // S_p: 8*4096*256 floats
  float* outA   = out + (size_t)B_ * (2 * L_) * D_;   // A region: 8*2048*2048 (holds E then A)

  // workspace layout (u16 elements)
  u16* w   = (u16*)d_ws;
  u16* xb  = w;                    // 4,194,304
  u16* Wb  = xb + 4194304;         //   196,608
  u16* Qb  = Wb + 196608;          // 4,194,304
  u16* Kb  = Qb + 4194304;         // 4,194,304
  u16* Vb  = Kb + 4194304;         // 4,194,304
  u16* Vbt = Vb + 4194304;         // 4,194,304
  u16* Ab  = Vbt + 4194304;        // 33,554,432
  float* mArr = (float*)(Ab + 33554432);    // 16384
  float* rArr = mArr + B_ * L_;             // 16384
  float* pm   = rArr + B_ * L_;             // 262144
  float* ps   = pm + 16 * B_ * L_;          // 262144

  cvt_kernel<<<4288, 256, 0, stream>>>(x, Wq, Wk, Wv, xb, Wb);
  qkv_gemm<<<dim3(128, 2, 3), 256, 0, stream>>>(xb, Wb, bq, bk, bv, Qb, Kb, Vb, out);
  transpose_v<<<dim3(32, 4, 8), 256, 0, stream>>>(Vb, Vbt);
  e_gemm<<<dim3(16, 16, 8), 256, 0, stream>>>(Qb, Kb, outA, pm, ps);
  stats_reduce<<<64, 256, 0, stream>>>(pm, ps, mArr, rArr);
  apply_kernel<<<32768, 256, 0, stream>>>(outA, Ab, mArr, rArr);
  av_gemm<<<dim3(16, 2, 8), 256, 0, stream>>>(Ab, Vbt, out);
}